// Round 1
// 400.296 us; speedup vs baseline: 1.3233x; 1.3233x over previous
//
#include <hip/hip_runtime.h>
#include <hip/hip_bf16.h>

#define N_NODES 100000
#define N_EDGES 1600000
#define DIM 128
#define NHEAD 8
#define HDIM 16

// Two-level CSR build: coarse buckets of 512 dst nodes each.
#define BSHIFT 9
#define BSZ 512
#define NB 196          // ceil(100000 / 512)
#define S1_EDGES 4096   // edges per block in bhist/bin

typedef __attribute__((ext_vector_type(8))) short short8;
typedef __attribute__((ext_vector_type(4))) float f32x4;

__device__ __forceinline__ unsigned short f2bf(float f) {
  union { __hip_bfloat16 h; unsigned short u; } c;
  c.h = __float2bfloat16(f);
  return c.u;
}

// Convert the three 128x128 weight matrices in one launch.
// y layout: [Wk | Wv | Wo], each 16384 elements (4096 float4 groups). 48 blocks x 256.
__global__ __launch_bounds__(256) void cvt3_kernel(const float* __restrict__ a,
                                                   const float* __restrict__ b,
                                                   const float* __restrict__ c,
                                                   unsigned short* __restrict__ y) {
  int i = blockIdx.x * 256 + threadIdx.x;  // 0..12287
  const float* src = (i < 4096) ? a : ((i < 8192) ? b : c);
  int j = (i < 4096) ? i : ((i < 8192) ? i - 4096 : i - 8192);
  float4 v = ((const float4*)src)[j];
  ushort4 o;
  o.x = f2bf(v.x); o.y = f2bf(v.y); o.z = f2bf(v.z); o.w = f2bf(v.w);
  ((ushort4*)y)[i] = o;
}

// ---------------- CSR construction (binned, cache-local) ----------------

// Coarse bucket histogram: LDS-reduced, <=196 global atomics per block.
__global__ __launch_bounds__(512) void bhist_kernel(const int* __restrict__ dst,
                                                    int* __restrict__ bcnt) {
  __shared__ int cnt[NB];
  int t = threadIdx.x;
  int base = blockIdx.x * S1_EDGES;
  if (t < NB) cnt[t] = 0;
  __syncthreads();
#pragma unroll
  for (int j = 0; j < S1_EDGES / 512; j++) {
    int e = base + j * 512 + t;
    if (e < N_EDGES) atomicAdd(&cnt[dst[e] >> BSHIFT], 1);
  }
  __syncthreads();
  if (t < NB) {
    int c = cnt[t];
    if (c) atomicAdd(&bcnt[t], c);
  }
}

// Exclusive scan of the 196 bucket counts -> binBase (== CSR segment bases).
__global__ __launch_bounds__(256) void bscan_kernel(const int* __restrict__ bcnt,
                                                    int* __restrict__ binBase,
                                                    int* __restrict__ binNext) {
  __shared__ int s[256];
  int t = threadIdx.x;
  int v = (t < NB) ? bcnt[t] : 0;
  s[t] = v;
  __syncthreads();
  for (int off = 1; off < 256; off <<= 1) {
    int x = (t >= off) ? s[t - off] : 0;
    __syncthreads();
    s[t] += x;
    __syncthreads();
  }
  int excl = (t == 0) ? 0 : s[t - 1];
  if (t <= NB) binBase[t] = excl;  // binBase[NB] = total = E
  if (t < NB) binNext[t] = excl;
}

// Block-local counting sort of 4096 edges into coarse buckets.
// Packed entry: src | (dst & 511) << 17  (src < 2^17, dstLow < 2^9).
__global__ __launch_bounds__(512) void bin_kernel(const int* __restrict__ src,
                                                  const int* __restrict__ dst,
                                                  int* __restrict__ binNext,
                                                  unsigned* __restrict__ binned) {
  __shared__ unsigned pk[S1_EDGES];
  __shared__ unsigned char bkt[S1_EDGES];
  __shared__ int cnt[NB], gb[NB], ln[NB];
  int t = threadIdx.x;
  int base = blockIdx.x * S1_EDGES;
  if (t < NB) { cnt[t] = 0; ln[t] = 0; }
  __syncthreads();
#pragma unroll
  for (int j = 0; j < S1_EDGES / 512; j++) {
    int idx = j * 512 + t;
    int e = base + idx;
    if (e < N_EDGES) {
      int s = src[e], d = dst[e];
      int bb = d >> BSHIFT;
      pk[idx] = (unsigned)s | ((unsigned)(d & (BSZ - 1)) << 17);
      bkt[idx] = (unsigned char)bb;
      atomicAdd(&cnt[bb], 1);
    } else {
      bkt[idx] = 0xFF;
    }
  }
  __syncthreads();
  if (t < NB) {
    int c = cnt[t];
    gb[t] = c ? atomicAdd(&binNext[t], c) : 0;
  }
  __syncthreads();
#pragma unroll
  for (int j = 0; j < S1_EDGES / 512; j++) {
    int idx = j * 512 + t;
    int bb = bkt[idx];
    if (bb != 0xFF) {
      int r = atomicAdd(&ln[bb], 1);
      binned[gb[bb] + r] = pk[idx];
    }
  }
}

// Per-bucket fine scatter: all per-dst ranking via LDS atomics; writes a
// disjoint contiguous ~32KB region of esrc + 512 rowptr entries per block.
__global__ __launch_bounds__(512) void fine_kernel(const unsigned* __restrict__ binned,
                                                   const int* __restrict__ binBase,
                                                   int* __restrict__ rowptr,
                                                   int* __restrict__ esrc) {
  __shared__ int cnt[BSZ], sc[BSZ], nxt[BSZ];
  int b = blockIdx.x, t = threadIdx.x;
  int beg = binBase[b], end = binBase[b + 1];
  cnt[t] = 0;
  __syncthreads();
  for (int i = beg + t; i < end; i += 512) atomicAdd(&cnt[binned[i] >> 17], 1);
  __syncthreads();
  int v = cnt[t];
  sc[t] = v;
  __syncthreads();
  for (int off = 1; off < 512; off <<= 1) {
    int x = (t >= off) ? sc[t - off] : 0;
    __syncthreads();
    sc[t] += x;
    __syncthreads();
  }
  int pos = beg + sc[t] - v;  // global CSR start for node b*512+t
  int node = b * BSZ + t;
  if (node <= N_NODES) rowptr[node] = pos;  // node==N lands on E naturally
  nxt[t] = pos;
  __syncthreads();
  for (int i = beg + t; i < end; i += 512) {
    unsigned p = binned[i];
    int r = atomicAdd(&nxt[p >> 17], 1);
    esrc[r] = (int)(p & 0x1FFFFu);
  }
}

// ---------------- K/V projection via bf16 MFMA (fused fp32->bf16 of A) ----------------
// KV row layout (256 shorts): slot 4p+0 = K[2p], 4p+1 = K[2p+1], 4p+2 = V[2p], 4p+3 = V[2p+1]
// so attn lane p fetches its K-pair AND V-pair with ONE dwordx2.
__global__ __launch_bounds__(256) void kv_proj_mfma(const float* __restrict__ A,
                                                    const unsigned short* __restrict__ Wk,
                                                    const float* __restrict__ bk,
                                                    const unsigned short* __restrict__ Wv,
                                                    const float* __restrict__ bv,
                                                    unsigned short* __restrict__ KV, int n) {
  int w = threadIdx.x >> 6, lane = threadIdx.x & 63;
  int m = lane & 15, quad = lane >> 4;
  int rbase = blockIdx.x * 64 + w * 16;
  int arow = rbase + m;
  if (arow >= n) arow = n - 1;
  const float* ap = A + (size_t)arow * DIM + quad * 8;
  short8 af[4];
#pragma unroll
  for (int t = 0; t < 4; t++) {
    float4 lo = *(const float4*)(ap + 32 * t);
    float4 hi = *(const float4*)(ap + 32 * t + 4);
    short8 f;
    f[0] = (short)f2bf(lo.x); f[1] = (short)f2bf(lo.y);
    f[2] = (short)f2bf(lo.z); f[3] = (short)f2bf(lo.w);
    f[4] = (short)f2bf(hi.x); f[5] = (short)f2bf(hi.y);
    f[6] = (short)f2bf(hi.z); f[7] = (short)f2bf(hi.w);
    af[t] = f;
  }
#pragma unroll
  for (int ct = 0; ct < 16; ct++) {
    const unsigned short* W = (ct < 8) ? Wk : Wv;
    const float* bias = (ct < 8) ? bk : bv;
    int c0 = (ct & 7) * 16;
    const unsigned short* wp = W + (size_t)(c0 + m) * DIM + quad * 8;
    f32x4 acc = {0.f, 0.f, 0.f, 0.f};
    acc = __builtin_amdgcn_mfma_f32_16x16x32_bf16(af[0], *(const short8*)(wp), acc, 0, 0, 0);
    acc = __builtin_amdgcn_mfma_f32_16x16x32_bf16(af[1], *(const short8*)(wp + 32), acc, 0, 0, 0);
    acc = __builtin_amdgcn_mfma_f32_16x16x32_bf16(af[2], *(const short8*)(wp + 64), acc, 0, 0, 0);
    acc = __builtin_amdgcn_mfma_f32_16x16x32_bf16(af[3], *(const short8*)(wp + 96), acc, 0, 0, 0);
    float bb = bias[c0 + m];
    int c = c0 + m;  // 0..127 within K or V
    int slot = ((ct < 8) ? 0 : 2) + 4 * (c >> 1) + (c & 1);
#pragma unroll
    for (int r = 0; r < 4; r++) {
      int rr = rbase + quad * 4 + r;
      if (rr < n) KV[(size_t)rr * 256 + slot] = f2bf(acc[r] + bb);
    }
  }
}

// ---------------- Output projection via bf16 MFMA ----------------
__global__ __launch_bounds__(256) void o_proj_mfma(const unsigned short* __restrict__ A,
                                                   const unsigned short* __restrict__ Wo,
                                                   const float* __restrict__ bo,
                                                   float* __restrict__ out, int n) {
  int w = threadIdx.x >> 6, lane = threadIdx.x & 63;
  int m = lane & 15, quad = lane >> 4;
  int rbase = blockIdx.x * 64 + w * 16;
  int arow = rbase + m;
  if (arow >= n) arow = n - 1;
  const unsigned short* ap = A + (size_t)arow * DIM + quad * 8;
  short8 af0 = *(const short8*)(ap);
  short8 af1 = *(const short8*)(ap + 32);
  short8 af2 = *(const short8*)(ap + 64);
  short8 af3 = *(const short8*)(ap + 96);
#pragma unroll
  for (int ct = 0; ct < 8; ct++) {
    int c0 = ct * 16;
    const unsigned short* wp = Wo + (size_t)(c0 + m) * DIM + quad * 8;
    f32x4 acc = {0.f, 0.f, 0.f, 0.f};
    acc = __builtin_amdgcn_mfma_f32_16x16x32_bf16(af0, *(const short8*)(wp), acc, 0, 0, 0);
    acc = __builtin_amdgcn_mfma_f32_16x16x32_bf16(af1, *(const short8*)(wp + 32), acc, 0, 0, 0);
    acc = __builtin_amdgcn_mfma_f32_16x16x32_bf16(af2, *(const short8*)(wp + 64), acc, 0, 0, 0);
    acc = __builtin_amdgcn_mfma_f32_16x16x32_bf16(af3, *(const short8*)(wp + 96), acc, 0, 0, 0);
    float bb = bo[c0 + m];
#pragma unroll
    for (int r = 0; r < 4; r++) {
      int rr = rbase + quad * 4 + r;
      if (rr < n) out[(size_t)rr * DIM + c0 + m] = acc[r] + bb;
    }
  }
}

// ---------------- Per-dst softmax attention, unrolled x4, fused KV gather ----------------
// One wave per destination node; lane p owns dims 2p,2p+1 (head = p>>3, shfl within 8 lanes).
// One dwordx2 per edge per lane: [K pair | V pair]. 4 edges' loads issued before consumption.
__global__ __launch_bounds__(256) void attn_kernel(const float* __restrict__ q,
                                                   const unsigned short* __restrict__ KV,
                                                   const int* __restrict__ rowptr,
                                                   const int* __restrict__ esrc,
                                                   unsigned short* __restrict__ pre) {
  int wid = blockIdx.x * 4 + __builtin_amdgcn_readfirstlane(threadIdx.x >> 6);
  int lane = threadIdx.x & 63;
  const float SCALE = 0.25f * 1.44269504088896340736f;  // 1/sqrt(16) * log2(e)
  float2 qv = *(const float2*)(q + (size_t)wid * DIM + lane * 2);
  float qx = qv.x * SCALE, qy = qv.y * SCALE;
  const unsigned short* base = KV + lane * 4;

  float l = 0.f, o0 = 0.f, o1 = 0.f;
  int beg = rowptr[wid], end = rowptr[wid + 1];

#define EDGE(d)                                                              \
  {                                                                          \
    float k0 = __uint_as_float((d).x << 16);                                 \
    float k1 = __uint_as_float((d).x & 0xffff0000u);                         \
    float part = fmaf(k1, qy, k0 * qx);                                      \
    part += __shfl_xor(part, 1);                                             \
    part += __shfl_xor(part, 2);                                             \
    part += __shfl_xor(part, 4);                                             \
    float e = exp2f(part);                                                   \
    l += e;                                                                  \
    o0 = fmaf(e, __uint_as_float((d).y << 16), o0);                          \
    o1 = fmaf(e, __uint_as_float((d).y & 0xffff0000u), o1);                  \
  }

  int i = beg;
  for (; i + 4 <= end; i += 4) {
    int s0 = esrc[i + 0], s1 = esrc[i + 1], s2 = esrc[i + 2], s3 = esrc[i + 3];
    uint2 d0 = *(const uint2*)(base + (size_t)s0 * 256);
    uint2 d1 = *(const uint2*)(base + (size_t)s1 * 256);
    uint2 d2 = *(const uint2*)(base + (size_t)s2 * 256);
    uint2 d3 = *(const uint2*)(base + (size_t)s3 * 256);
    EDGE(d0) EDGE(d1) EDGE(d2) EDGE(d3)
  }
  for (; i < end; ++i) {
    int s = esrc[i];
    uint2 d = *(const uint2*)(base + (size_t)s * 256);
    EDGE(d)
  }
#undef EDGE

  float inv = __builtin_amdgcn_rcpf(l + 1e-16f);
  ushort2 r;
  r.x = f2bf(o0 * inv);
  r.y = f2bf(o1 * inv);
  *(ushort2*)(pre + (size_t)wid * DIM + lane * 2) = r;
}

// ---------------- launch ----------------

extern "C" void kernel_launch(void* const* d_in, const int* in_sizes, int n_in,
                              void* d_out, int out_size, void* d_ws, size_t ws_size,
                              hipStream_t stream) {
  const float* q  = (const float*)d_in[0];
  const float* kv = (const float*)d_in[1];
  const int* ei   = (const int*)d_in[2];
  const float* Wk = (const float*)d_in[3];
  const float* bk = (const float*)d_in[4];
  const float* Wv = (const float*)d_in[5];
  const float* bv = (const float*)d_in[6];
  const float* Wo = (const float*)d_in[7];
  const float* bo = (const float*)d_in[8];
  float* out = (float*)d_out;
  const int* srcp = ei;            // edge_index[0]
  const int* dstp = ei + N_EDGES;  // edge_index[1]

  char* ws = (char*)d_ws;
  size_t o = 0;
  auto alloc = [&](size_t bytes) {
    void* p = ws + o;
    o += (bytes + 511) & ~(size_t)511;
    return p;
  };
  unsigned short* Wkb = (unsigned short*)alloc((size_t)DIM * DIM * 2);      // contiguous:
  unsigned short* Wvb = (unsigned short*)alloc((size_t)DIM * DIM * 2);      //   32768 B each
  unsigned short* Wob = (unsigned short*)alloc((size_t)DIM * DIM * 2);
  unsigned short* KV  = (unsigned short*)alloc((size_t)N_NODES * 256 * 2);  // 51.2 MB
  unsigned short* pre = (unsigned short*)alloc((size_t)N_NODES * DIM * 2);  // 25.6 MB
  int* esrc      = (int*)alloc((size_t)N_EDGES * 4);
  unsigned* binned = (unsigned*)alloc((size_t)N_EDGES * 4);                 // 6.4 MB
  int* rowptr    = (int*)alloc((size_t)(N_NODES + 1) * 4);
  int* bcnt      = (int*)alloc((size_t)NB * 4);
  int* binBase   = (int*)alloc((size_t)(NB + 1) * 4);
  int* binNext   = (int*)alloc((size_t)NB * 4);
  (void)ws_size;  // ~91 MB

  hipMemsetAsync(bcnt, 0, (size_t)NB * 4, stream);
  cvt3_kernel<<<48, 256, 0, stream>>>(Wk, Wv, Wo, Wkb);  // Wkb|Wvb|Wob contiguous
  // CSR build: coarse-bucket histogram -> scan -> bin -> per-bucket fine scatter
  int nbblk = (N_EDGES + S1_EDGES - 1) / S1_EDGES;  // 391
  bhist_kernel<<<nbblk, 512, 0, stream>>>(dstp, bcnt);
  bscan_kernel<<<1, 256, 0, stream>>>(bcnt, binBase, binNext);
  bin_kernel<<<nbblk, 512, 0, stream>>>(srcp, dstp, binNext, binned);
  fine_kernel<<<NB, 512, 0, stream>>>(binned, binBase, rowptr, esrc);
  // projections + attention
  kv_proj_mfma<<<(N_NODES + 63) / 64, 256, 0, stream>>>(kv, Wkb, bk, Wvb, bv, KV, N_NODES);
  attn_kernel<<<N_NODES / 4, 256, 0, stream>>>(q, KV, rowptr, esrc, pre);
  o_proj_mfma<<<(N_NODES + 63) / 64, 256, 0, stream>>>(pre, Wob, bo, out, N_NODES);
}

// Round 3
// 386.563 us; speedup vs baseline: 1.3703x; 1.0355x over previous
//
#include <hip/hip_runtime.h>
#include <hip/hip_bf16.h>

#define N_NODES 100000
#define N_EDGES 1600000
#define DIM 128
#define NHEAD 8
#define HDIM 16

// Two-level CSR build: coarse buckets of 512 dst nodes each.
#define BSHIFT 9
#define BSZ 512
#define NB 196          // ceil(100000 / 512)
#define S1_EDGES 4096   // edges per block in bhist/bin

typedef __attribute__((ext_vector_type(8))) short short8;
typedef __attribute__((ext_vector_type(4))) float f32x4;

__device__ __forceinline__ unsigned short f2bf(float f) {
  union { __hip_bfloat16 h; unsigned short u; } c;
  c.h = __float2bfloat16(f);
  return c.u;
}

// Convert the three 128x128 weight matrices in one launch.
// y layout: [Wk | Wv | Wo], each 16384 elements (4096 float4 groups). 48 blocks x 256.
__global__ __launch_bounds__(256) void cvt3_kernel(const float* __restrict__ a,
                                                   const float* __restrict__ b,
                                                   const float* __restrict__ c,
                                                   unsigned short* __restrict__ y) {
  int i = blockIdx.x * 256 + threadIdx.x;  // 0..12287
  const float* src = (i < 4096) ? a : ((i < 8192) ? b : c);
  int j = (i < 4096) ? i : ((i < 8192) ? i - 4096 : i - 8192);
  float4 v = ((const float4*)src)[j];
  ushort4 o;
  o.x = f2bf(v.x); o.y = f2bf(v.y); o.z = f2bf(v.z); o.w = f2bf(v.w);
  ((ushort4*)y)[i] = o;
}

// ---------------- CSR construction (binned, cache-local) ----------------

// Coarse bucket histogram: LDS-reduced, <=196 global atomics per block.
__global__ __launch_bounds__(512) void bhist_kernel(const int* __restrict__ dst,
                                                    int* __restrict__ bcnt) {
  __shared__ int cnt[NB];
  int t = threadIdx.x;
  int base = blockIdx.x * S1_EDGES;
  if (t < NB) cnt[t] = 0;
  __syncthreads();
#pragma unroll
  for (int j = 0; j < S1_EDGES / 512; j++) {
    int e = base + j * 512 + t;
    if (e < N_EDGES) atomicAdd(&cnt[dst[e] >> BSHIFT], 1);
  }
  __syncthreads();
  if (t < NB) {
    int c = cnt[t];
    if (c) atomicAdd(&bcnt[t], c);
  }
}

// Exclusive scan of the 196 bucket counts -> binBase (== CSR segment bases).
__global__ __launch_bounds__(256) void bscan_kernel(const int* __restrict__ bcnt,
                                                    int* __restrict__ binBase,
                                                    int* __restrict__ binNext) {
  __shared__ int s[256];
  int t = threadIdx.x;
  int v = (t < NB) ? bcnt[t] : 0;
  s[t] = v;
  __syncthreads();
  for (int off = 1; off < 256; off <<= 1) {
    int x = (t >= off) ? s[t - off] : 0;
    __syncthreads();
    s[t] += x;
    __syncthreads();
  }
  int excl = (t == 0) ? 0 : s[t - 1];
  if (t <= NB) binBase[t] = excl;  // binBase[NB] = total = E
  if (t < NB) binNext[t] = excl;
}

// Block-local counting sort of 4096 edges into coarse buckets.
// Packed entry: src | (dst & 511) << 17  (src < 2^17, dstLow < 2^9).
__global__ __launch_bounds__(512) void bin_kernel(const int* __restrict__ src,
                                                  const int* __restrict__ dst,
                                                  int* __restrict__ binNext,
                                                  unsigned* __restrict__ binned) {
  __shared__ unsigned pk[S1_EDGES];
  __shared__ unsigned char bkt[S1_EDGES];
  __shared__ int cnt[NB], gb[NB], ln[NB];
  int t = threadIdx.x;
  int base = blockIdx.x * S1_EDGES;
  if (t < NB) { cnt[t] = 0; ln[t] = 0; }
  __syncthreads();
#pragma unroll
  for (int j = 0; j < S1_EDGES / 512; j++) {
    int idx = j * 512 + t;
    int e = base + idx;
    if (e < N_EDGES) {
      int s = src[e], d = dst[e];
      int bb = d >> BSHIFT;
      pk[idx] = (unsigned)s | ((unsigned)(d & (BSZ - 1)) << 17);
      bkt[idx] = (unsigned char)bb;
      atomicAdd(&cnt[bb], 1);
    } else {
      bkt[idx] = 0xFF;
    }
  }
  __syncthreads();
  if (t < NB) {
    int c = cnt[t];
    gb[t] = c ? atomicAdd(&binNext[t], c) : 0;
  }
  __syncthreads();
#pragma unroll
  for (int j = 0; j < S1_EDGES / 512; j++) {
    int idx = j * 512 + t;
    int bb = bkt[idx];
    if (bb != 0xFF) {
      int r = atomicAdd(&ln[bb], 1);
      binned[gb[bb] + r] = pk[idx];
    }
  }
}

// Per-bucket fine scatter: all per-dst ranking via LDS atomics; writes a
// disjoint contiguous ~32KB region of esrc + 512 rowptr entries per block.
__global__ __launch_bounds__(512) void fine_kernel(const unsigned* __restrict__ binned,
                                                   const int* __restrict__ binBase,
                                                   int* __restrict__ rowptr,
                                                   int* __restrict__ esrc) {
  __shared__ int cnt[BSZ], sc[BSZ], nxt[BSZ];
  int b = blockIdx.x, t = threadIdx.x;
  int beg = binBase[b], end = binBase[b + 1];
  cnt[t] = 0;
  __syncthreads();
  for (int i = beg + t; i < end; i += 512) atomicAdd(&cnt[binned[i] >> 17], 1);
  __syncthreads();
  int v = cnt[t];
  sc[t] = v;
  __syncthreads();
  for (int off = 1; off < 512; off <<= 1) {
    int x = (t >= off) ? sc[t - off] : 0;
    __syncthreads();
    sc[t] += x;
    __syncthreads();
  }
  int pos = beg + sc[t] - v;  // global CSR start for node b*512+t
  int node = b * BSZ + t;
  if (node <= N_NODES) rowptr[node] = pos;  // node==N lands on E naturally
  nxt[t] = pos;
  __syncthreads();
  for (int i = beg + t; i < end; i += 512) {
    unsigned p = binned[i];
    int r = atomicAdd(&nxt[p >> 17], 1);
    esrc[r] = (int)(p & 0x1FFFFu);
  }
}

// ---------------- K/V projection via bf16 MFMA (fused fp32->bf16 of A) ----------------
// KV row layout (256 shorts): for lane p in [0,32): shorts 8p+0..3 = K[4p..4p+3],
// shorts 8p+4..7 = V[4p..4p+3] -> attn lane p fetches K-quad AND V-quad with ONE dwordx4.
// Results staged in LDS, flushed with coalesced 16B/lane stores.
__global__ __launch_bounds__(256) void kv_proj_mfma(const float* __restrict__ A,
                                                    const unsigned short* __restrict__ Wk,
                                                    const float* __restrict__ bk,
                                                    const unsigned short* __restrict__ Wv,
                                                    const float* __restrict__ bv,
                                                    unsigned short* __restrict__ KV, int n) {
  __shared__ unsigned short tile[64][264];  // 264 = 256 + 8 pad (bank spread)
  int w = threadIdx.x >> 6, lane = threadIdx.x & 63;
  int m = lane & 15, quad = lane >> 4;
  int rbase = blockIdx.x * 64 + w * 16;
  int arow = rbase + m;
  if (arow >= n) arow = n - 1;
  const float* ap = A + (size_t)arow * DIM + quad * 8;
  short8 af[4];
#pragma unroll
  for (int t = 0; t < 4; t++) {
    float4 lo = *(const float4*)(ap + 32 * t);
    float4 hi = *(const float4*)(ap + 32 * t + 4);
    short8 f;
    f[0] = (short)f2bf(lo.x); f[1] = (short)f2bf(lo.y);
    f[2] = (short)f2bf(lo.z); f[3] = (short)f2bf(lo.w);
    f[4] = (short)f2bf(hi.x); f[5] = (short)f2bf(hi.y);
    f[6] = (short)f2bf(hi.z); f[7] = (short)f2bf(hi.w);
    af[t] = f;
  }
#pragma unroll
  for (int ct = 0; ct < 16; ct++) {
    const unsigned short* W = (ct < 8) ? Wk : Wv;
    const float* bias = (ct < 8) ? bk : bv;
    int c0 = (ct & 7) * 16;
    const unsigned short* wp = W + (size_t)(c0 + m) * DIM + quad * 8;
    f32x4 acc = {0.f, 0.f, 0.f, 0.f};
    acc = __builtin_amdgcn_mfma_f32_16x16x32_bf16(af[0], *(const short8*)(wp), acc, 0, 0, 0);
    acc = __builtin_amdgcn_mfma_f32_16x16x32_bf16(af[1], *(const short8*)(wp + 32), acc, 0, 0, 0);
    acc = __builtin_amdgcn_mfma_f32_16x16x32_bf16(af[2], *(const short8*)(wp + 64), acc, 0, 0, 0);
    acc = __builtin_amdgcn_mfma_f32_16x16x32_bf16(af[3], *(const short8*)(wp + 96), acc, 0, 0, 0);
    float bb = bias[c0 + m];
    int c = c0 + m;  // 0..127 within K or V
    int pos = ((ct < 8) ? 0 : 4) + (c >> 2) * 8 + (c & 3);
    int lr = w * 16 + quad * 4;
#pragma unroll
    for (int r = 0; r < 4; r++) tile[lr + r][pos] = f2bf(acc[r] + bb);
  }
  __syncthreads();
  // Coalesced flush: 2048 chunks of 16B; 8 iters x 256 threads.
#pragma unroll
  for (int it = 0; it < 8; it++) {
    int cidx = it * 256 + threadIdx.x;  // 0..2047
    int row = cidx >> 5;                // 0..63
    int off = (cidx & 31) * 8;          // shorts
    int g = blockIdx.x * 64 + row;
    if (g < n)
      *(uint4*)(KV + (size_t)g * 256 + off) = *(const uint4*)(&tile[row][off]);
  }
}

// ---------------- Output projection via bf16 MFMA ----------------
__global__ __launch_bounds__(256) void o_proj_mfma(const unsigned short* __restrict__ A,
                                                   const unsigned short* __restrict__ Wo,
                                                   const float* __restrict__ bo,
                                                   float* __restrict__ out, int n) {
  int w = threadIdx.x >> 6, lane = threadIdx.x & 63;
  int m = lane & 15, quad = lane >> 4;
  int rbase = blockIdx.x * 64 + w * 16;
  int arow = rbase + m;
  if (arow >= n) arow = n - 1;
  const unsigned short* ap = A + (size_t)arow * DIM + quad * 8;
  short8 af0 = *(const short8*)(ap);
  short8 af1 = *(const short8*)(ap + 32);
  short8 af2 = *(const short8*)(ap + 64);
  short8 af3 = *(const short8*)(ap + 96);
#pragma unroll
  for (int ct = 0; ct < 8; ct++) {
    int c0 = ct * 16;
    const unsigned short* wp = Wo + (size_t)(c0 + m) * DIM + quad * 8;
    f32x4 acc = {0.f, 0.f, 0.f, 0.f};
    acc = __builtin_amdgcn_mfma_f32_16x16x32_bf16(af0, *(const short8*)(wp), acc, 0, 0, 0);
    acc = __builtin_amdgcn_mfma_f32_16x16x32_bf16(af1, *(const short8*)(wp + 32), acc, 0, 0, 0);
    acc = __builtin_amdgcn_mfma_f32_16x16x32_bf16(af2, *(const short8*)(wp + 64), acc, 0, 0, 0);
    acc = __builtin_amdgcn_mfma_f32_16x16x32_bf16(af3, *(const short8*)(wp + 96), acc, 0, 0, 0);
    float bb = bo[c0 + m];
#pragma unroll
    for (int r = 0; r < 4; r++) {
      int rr = rbase + quad * 4 + r;
      if (rr < n) out[(size_t)rr * DIM + c0 + m] = acc[r] + bb;
    }
  }
}

// ---------------- Per-dst softmax attention ----------------
// One wave per destination node. Lane p = lane&31 owns dims 4p..4p+3 (head = p>>2).
// The two 32-lane halves process TWO edges per step: one dwordx4 (K-quad|V-quad)
// per lane per edge-pair. 8 edges (4 loads) in flight per unrolled iteration.
// Epilogue combines halves with shfl_xor(.,32).
__global__ __launch_bounds__(256) void attn_kernel(const float* __restrict__ q,
                                                   const unsigned short* __restrict__ KV,
                                                   const int* __restrict__ rowptr,
                                                   const int* __restrict__ esrc,
                                                   unsigned short* __restrict__ pre) {
  int wid = blockIdx.x * 4 + __builtin_amdgcn_readfirstlane(threadIdx.x >> 6);
  int lane = threadIdx.x & 63;
  int half = lane >> 5;   // 0: even edges, 1: odd edges
  int p = lane & 31;      // dim-quad owner
  const float SCALE = 0.25f * 1.44269504088896340736f;  // 1/sqrt(16) * log2(e)
  float4 qv = *(const float4*)(q + (size_t)wid * DIM + p * 4);
  float qx = qv.x * SCALE, qy = qv.y * SCALE, qz = qv.z * SCALE, qw = qv.w * SCALE;
  const unsigned short* base = KV + p * 8;

  float l = 0.f, o0 = 0.f, o1 = 0.f, o2 = 0.f, o3 = 0.f;
  int beg = rowptr[wid], end = rowptr[wid + 1];

#define EDGE2(d, wgt)                                                        \
  {                                                                          \
    float k0 = __uint_as_float((d).x << 16);                                 \
    float k1 = __uint_as_float((d).x & 0xffff0000u);                         \
    float k2 = __uint_as_float((d).y << 16);                                 \
    float k3 = __uint_as_float((d).y & 0xffff0000u);                         \
    float part = fmaf(k1, qy, k0 * qx);                                      \
    part = fmaf(k3, qw, fmaf(k2, qz, part));                                 \
    part += __shfl_xor(part, 1);                                             \
    part += __shfl_xor(part, 2);                                             \
    float e = exp2f(part) * (wgt);                                           \
    l += e;                                                                  \
    o0 = fmaf(e, __uint_as_float((d).z << 16), o0);                          \
    o1 = fmaf(e, __uint_as_float((d).z & 0xffff0000u), o1);                  \
    o2 = fmaf(e, __uint_as_float((d).w << 16), o2);                          \
    o3 = fmaf(e, __uint_as_float((d).w & 0xffff0000u), o3);                  \
  }

  int i = beg;
  for (; i + 8 <= end; i += 8) {
    int4 sa = *(const int4*)(esrc + i);      // wave-uniform
    int4 sb = *(const int4*)(esrc + i + 4);
    int s0 = half ? sa.y : sa.x;
    int s1 = half ? sa.w : sa.z;
    int s2 = half ? sb.y : sb.x;
    int s3 = half ? sb.w : sb.z;
    uint4 d0 = *(const uint4*)(base + (size_t)s0 * 256);
    uint4 d1 = *(const uint4*)(base + (size_t)s1 * 256);
    uint4 d2 = *(const uint4*)(base + (size_t)s2 * 256);
    uint4 d3 = *(const uint4*)(base + (size_t)s3 * 256);
    EDGE2(d0, 1.f) EDGE2(d1, 1.f) EDGE2(d2, 1.f) EDGE2(d3, 1.f)
  }
  for (; i + 2 <= end; i += 2) {
    int s = esrc[i + half];
    uint4 d = *(const uint4*)(base + (size_t)s * 256);
    EDGE2(d, 1.f)
  }
  if (i < end) {  // odd tail: both halves load the same edge; half 1 masked out
    int s = esrc[i];
    uint4 d = *(const uint4*)(base + (size_t)s * 256);
    float hm = half ? 0.f : 1.f;
    EDGE2(d, hm)
  }
#undef EDGE2

  // combine the two halves
  l += __shfl_xor(l, 32);
  o0 += __shfl_xor(o0, 32);
  o1 += __shfl_xor(o1, 32);
  o2 += __shfl_xor(o2, 32);
  o3 += __shfl_xor(o3, 32);

  float inv = __builtin_amdgcn_rcpf(l + 1e-16f);
  if (half == 0) {
    ushort4 r;
    r.x = f2bf(o0 * inv);
    r.y = f2bf(o1 * inv);
    r.z = f2bf(o2 * inv);
    r.w = f2bf(o3 * inv);
    *(ushort4*)(pre + (size_t)wid * DIM + p * 4) = r;
  }
}

// ---------------- launch ----------------

extern "C" void kernel_launch(void* const* d_in, const int* in_sizes, int n_in,
                              void* d_out, int out_size, void* d_ws, size_t ws_size,
                              hipStream_t stream) {
  const float* q  = (const float*)d_in[0];
  const float* kv = (const float*)d_in[1];
  const int* ei   = (const int*)d_in[2];
  const float* Wk = (const float*)d_in[3];
  const float* bk = (const float*)d_in[4];
  const float* Wv = (const float*)d_in[5];
  const float* bv = (const float*)d_in[6];
  const float* Wo = (const float*)d_in[7];
  const float* bo = (const float*)d_in[8];
  float* out = (float*)d_out;
  const int* srcp = ei;            // edge_index[0]
  const int* dstp = ei + N_EDGES;  // edge_index[1]

  char* ws = (char*)d_ws;
  size_t o = 0;
  auto alloc = [&](size_t bytes) {
    void* p = ws + o;
    o += (bytes + 511) & ~(size_t)511;
    return p;
  };
  unsigned short* Wkb = (unsigned short*)alloc((size_t)DIM * DIM * 2);      // contiguous:
  unsigned short* Wvb = (unsigned short*)alloc((size_t)DIM * DIM * 2);      //   32768 B each
  unsigned short* Wob = (unsigned short*)alloc((size_t)DIM * DIM * 2);
  unsigned short* KV  = (unsigned short*)alloc((size_t)N_NODES * 256 * 2);  // 51.2 MB
  unsigned short* pre = (unsigned short*)alloc((size_t)N_NODES * DIM * 2);  // 25.6 MB
  int* esrc      = (int*)alloc((size_t)N_EDGES * 4);
  unsigned* binned = (unsigned*)alloc((size_t)N_EDGES * 4);                 // 6.4 MB
  int* rowptr    = (int*)alloc((size_t)(N_NODES + 1) * 4);
  int* bcnt      = (int*)alloc((size_t)NB * 4);
  int* binBase   = (int*)alloc((size_t)(NB + 1) * 4);
  int* binNext   = (int*)alloc((size_t)NB * 4);
  (void)ws_size;  // ~91 MB

  hipMemsetAsync(bcnt, 0, (size_t)NB * 4, stream);
  cvt3_kernel<<<48, 256, 0, stream>>>(Wk, Wv, Wo, Wkb);  // Wkb|Wvb|Wob contiguous
  // CSR build: coarse-bucket histogram -> scan -> bin -> per-bucket fine scatter
  int nbblk = (N_EDGES + S1_EDGES - 1) / S1_EDGES;  // 391
  bhist_kernel<<<nbblk, 512, 0, stream>>>(dstp, bcnt);
  bscan_kernel<<<1, 256, 0, stream>>>(bcnt, binBase, binNext);
  bin_kernel<<<nbblk, 512, 0, stream>>>(srcp, dstp, binNext, binned);
  fine_kernel<<<NB, 512, 0, stream>>>(binned, binBase, rowptr, esrc);
  // projections + attention
  kv_proj_mfma<<<(N_NODES + 63) / 64, 256, 0, stream>>>(kv, Wkb, bk, Wvb, bv, KV, N_NODES);
  attn_kernel<<<N_NODES / 4, 256, 0, stream>>>(q, KV, rowptr, esrc, pre);
  o_proj_mfma<<<(N_NODES + 63) / 64, 256, 0, stream>>>(pre, Wob, bo, out, N_NODES);
}

// Round 7
// 385.313 us; speedup vs baseline: 1.3748x; 1.0032x over previous
//
#include <hip/hip_runtime.h>
#include <hip/hip_bf16.h>

#define N_NODES 100000
#define N_EDGES 1600000
#define DIM 128
#define NHEAD 8
#define HDIM 16

// Two-level CSR build: coarse buckets of 512 dst nodes each.
#define BSHIFT 9
#define BSZ 512
#define NB 196          // ceil(100000 / 512)
#define S1_EDGES 4096   // edges per block in bhist/bin

typedef __attribute__((ext_vector_type(8))) short short8;
typedef __attribute__((ext_vector_type(4))) float f32x4;

__device__ __forceinline__ unsigned short f2bf(float f) {
  union { __hip_bfloat16 h; unsigned short u; } c;
  c.h = __float2bfloat16(f);
  return c.u;
}

// Convert the three 128x128 weight matrices in one launch.
// y layout: [Wk | Wv | Wo], each 16384 elements (4096 float4 groups). 48 blocks x 256.
__global__ __launch_bounds__(256) void cvt3_kernel(const float* __restrict__ a,
                                                   const float* __restrict__ b,
                                                   const float* __restrict__ c,
                                                   unsigned short* __restrict__ y) {
  int i = blockIdx.x * 256 + threadIdx.x;  // 0..12287
  const float* src = (i < 4096) ? a : ((i < 8192) ? b : c);
  int j = (i < 4096) ? i : ((i < 8192) ? i - 4096 : i - 8192);
  float4 v = ((const float4*)src)[j];
  ushort4 o;
  o.x = f2bf(v.x); o.y = f2bf(v.y); o.z = f2bf(v.z); o.w = f2bf(v.w);
  ((ushort4*)y)[i] = o;
}

// ---------------- CSR construction (binned, cache-local) ----------------

// Coarse bucket histogram: LDS-reduced, <=196 global atomics per block.
__global__ __launch_bounds__(512) void bhist_kernel(const int* __restrict__ dst,
                                                    int* __restrict__ bcnt) {
  __shared__ int cnt[NB];
  int t = threadIdx.x;
  int base = blockIdx.x * S1_EDGES;
  if (t < NB) cnt[t] = 0;
  __syncthreads();
#pragma unroll
  for (int j = 0; j < S1_EDGES / 512; j++) {
    int e = base + j * 512 + t;
    if (e < N_EDGES) atomicAdd(&cnt[dst[e] >> BSHIFT], 1);
  }
  __syncthreads();
  if (t < NB) {
    int c = cnt[t];
    if (c) atomicAdd(&bcnt[t], c);
  }
}

// Exclusive scan of the 196 bucket counts -> binBase (== CSR segment bases).
__global__ __launch_bounds__(256) void bscan_kernel(const int* __restrict__ bcnt,
                                                    int* __restrict__ binBase,
                                                    int* __restrict__ binNext) {
  __shared__ int s[256];
  int t = threadIdx.x;
  int v = (t < NB) ? bcnt[t] : 0;
  s[t] = v;
  __syncthreads();
  for (int off = 1; off < 256; off <<= 1) {
    int x = (t >= off) ? s[t - off] : 0;
    __syncthreads();
    s[t] += x;
    __syncthreads();
  }
  int excl = (t == 0) ? 0 : s[t - 1];
  if (t <= NB) binBase[t] = excl;  // binBase[NB] = total = E
  if (t < NB) binNext[t] = excl;
}

// Block-local counting sort of 4096 edges into coarse buckets.
// Packed entry: src | (dst & 511) << 17  (src < 2^17, dstLow < 2^9).
__global__ __launch_bounds__(512) void bin_kernel(const int* __restrict__ src,
                                                  const int* __restrict__ dst,
                                                  int* __restrict__ binNext,
                                                  unsigned* __restrict__ binned) {
  __shared__ unsigned pk[S1_EDGES];
  __shared__ unsigned char bkt[S1_EDGES];
  __shared__ int cnt[NB], gb[NB], ln[NB];
  int t = threadIdx.x;
  int base = blockIdx.x * S1_EDGES;
  if (t < NB) { cnt[t] = 0; ln[t] = 0; }
  __syncthreads();
#pragma unroll
  for (int j = 0; j < S1_EDGES / 512; j++) {
    int idx = j * 512 + t;
    int e = base + idx;
    if (e < N_EDGES) {
      int s = src[e], d = dst[e];
      int bb = d >> BSHIFT;
      pk[idx] = (unsigned)s | ((unsigned)(d & (BSZ - 1)) << 17);
      bkt[idx] = (unsigned char)bb;
      atomicAdd(&cnt[bb], 1);
    } else {
      bkt[idx] = 0xFF;
    }
  }
  __syncthreads();
  if (t < NB) {
    int c = cnt[t];
    gb[t] = c ? atomicAdd(&binNext[t], c) : 0;
  }
  __syncthreads();
#pragma unroll
  for (int j = 0; j < S1_EDGES / 512; j++) {
    int idx = j * 512 + t;
    int bb = bkt[idx];
    if (bb != 0xFF) {
      int r = atomicAdd(&ln[bb], 1);
      binned[gb[bb] + r] = pk[idx];
    }
  }
}

// Per-bucket fine scatter: all per-dst ranking via LDS atomics; writes a
// disjoint contiguous ~32KB region of esrc + 512 rowptr entries per block.
__global__ __launch_bounds__(512) void fine_kernel(const unsigned* __restrict__ binned,
                                                   const int* __restrict__ binBase,
                                                   int* __restrict__ rowptr,
                                                   int* __restrict__ esrc) {
  __shared__ int cnt[BSZ], sc[BSZ], nxt[BSZ];
  int b = blockIdx.x, t = threadIdx.x;
  int beg = binBase[b], end = binBase[b + 1];
  cnt[t] = 0;
  __syncthreads();
  for (int i = beg + t; i < end; i += 512) atomicAdd(&cnt[binned[i] >> 17], 1);
  __syncthreads();
  int v = cnt[t];
  sc[t] = v;
  __syncthreads();
  for (int off = 1; off < 512; off <<= 1) {
    int x = (t >= off) ? sc[t - off] : 0;
    __syncthreads();
    sc[t] += x;
    __syncthreads();
  }
  int pos = beg + sc[t] - v;  // global CSR start for node b*512+t
  int node = b * BSZ + t;
  if (node <= N_NODES) rowptr[node] = pos;  // node==N lands on E naturally
  nxt[t] = pos;
  __syncthreads();
  for (int i = beg + t; i < end; i += 512) {
    unsigned p = binned[i];
    int r = atomicAdd(&nxt[p >> 17], 1);
    esrc[r] = (int)(p & 0x1FFFFu);
  }
}

// ---------------- K/V projection via bf16 MFMA (fused fp32->bf16 of A) ----------------
// KV row layout (256 shorts): for lane p in [0,32): shorts 8p+0..3 = K[4p..4p+3],
// shorts 8p+4..7 = V[4p..4p+3] -> attn lane p fetches K-quad AND V-quad with ONE dwordx4.
// Results staged in LDS, flushed with coalesced 16B/lane stores.
__global__ __launch_bounds__(256) void kv_proj_mfma(const float* __restrict__ A,
                                                    const unsigned short* __restrict__ Wk,
                                                    const float* __restrict__ bk,
                                                    const unsigned short* __restrict__ Wv,
                                                    const float* __restrict__ bv,
                                                    unsigned short* __restrict__ KV, int n) {
  __shared__ unsigned short tile[64][264];  // 264 = 256 + 8 pad (bank spread)
  int w = threadIdx.x >> 6, lane = threadIdx.x & 63;
  int m = lane & 15, quad = lane >> 4;
  int rbase = blockIdx.x * 64 + w * 16;
  int arow = rbase + m;
  if (arow >= n) arow = n - 1;
  const float* ap = A + (size_t)arow * DIM + quad * 8;
  short8 af[4];
#pragma unroll
  for (int t = 0; t < 4; t++) {
    float4 lo = *(const float4*)(ap + 32 * t);
    float4 hi = *(const float4*)(ap + 32 * t + 4);
    short8 f;
    f[0] = (short)f2bf(lo.x); f[1] = (short)f2bf(lo.y);
    f[2] = (short)f2bf(lo.z); f[3] = (short)f2bf(lo.w);
    f[4] = (short)f2bf(hi.x); f[5] = (short)f2bf(hi.y);
    f[6] = (short)f2bf(hi.z); f[7] = (short)f2bf(hi.w);
    af[t] = f;
  }
#pragma unroll
  for (int ct = 0; ct < 16; ct++) {
    const unsigned short* W = (ct < 8) ? Wk : Wv;
    const float* bias = (ct < 8) ? bk : bv;
    int c0 = (ct & 7) * 16;
    const unsigned short* wp = W + (size_t)(c0 + m) * DIM + quad * 8;
    f32x4 acc = {0.f, 0.f, 0.f, 0.f};
    acc = __builtin_amdgcn_mfma_f32_16x16x32_bf16(af[0], *(const short8*)(wp), acc, 0, 0, 0);
    acc = __builtin_amdgcn_mfma_f32_16x16x32_bf16(af[1], *(const short8*)(wp + 32), acc, 0, 0, 0);
    acc = __builtin_amdgcn_mfma_f32_16x16x32_bf16(af[2], *(const short8*)(wp + 64), acc, 0, 0, 0);
    acc = __builtin_amdgcn_mfma_f32_16x16x32_bf16(af[3], *(const short8*)(wp + 96), acc, 0, 0, 0);
    float bb = bias[c0 + m];
    int c = c0 + m;  // 0..127 within K or V
    int pos = ((ct < 8) ? 0 : 4) + (c >> 2) * 8 + (c & 3);
    int lr = w * 16 + quad * 4;
#pragma unroll
    for (int r = 0; r < 4; r++) tile[lr + r][pos] = f2bf(acc[r] + bb);
  }
  __syncthreads();
  // Coalesced flush: 2048 chunks of 16B; 8 iters x 256 threads.
#pragma unroll
  for (int it = 0; it < 8; it++) {
    int cidx = it * 256 + threadIdx.x;  // 0..2047
    int row = cidx >> 5;                // 0..63
    int off = (cidx & 31) * 8;          // shorts
    int g = blockIdx.x * 64 + row;
    if (g < n)
      *(uint4*)(KV + (size_t)g * 256 + off) = *(const uint4*)(&tile[row][off]);
  }
}

// ---------------- Fused attention + output projection ----------------
// Block = 256 threads (4 waves) handles 16 consecutive dst nodes.
// Phase 1: waves dynamically grab dst nodes (LDS ticket) and run the per-dst
//   softmax-attention gather loop (identical structure to the previous
//   attn_kernel); normalized bf16 results land in an LDS tile [16][136].
// Phase 2: 16x128 o_proj MFMA epilogue; wave w computes column-tiles 2w,2w+1.
// This removes the 'pre' HBM round-trip (51 MB) and the o_proj dispatch.
__global__ __launch_bounds__(256) void attn_oproj_kernel(const float* __restrict__ q,
                                                         const unsigned short* __restrict__ KV,
                                                         const int* __restrict__ rowptr,
                                                         const int* __restrict__ esrc,
                                                         const unsigned short* __restrict__ Wo,
                                                         const float* __restrict__ bo,
                                                         float* __restrict__ out,
                                                         int nodeBase) {
  __shared__ unsigned short tile[16][136];  // 272B row stride: 16B-aligned rows
  __shared__ int nextT;
  int tid = threadIdx.x;
  int wlane = tid & 63;
  int half = wlane >> 5;  // 0: even edges, 1: odd edges
  int p = wlane & 31;     // dim-quad owner
  if (tid == 0) nextT = 0;
  __syncthreads();
  int rowBase = nodeBase + blockIdx.x * 16;
  const float SCALE = 0.25f * 1.44269504088896340736f;  // 1/sqrt(16) * log2(e)
  const unsigned short* base = KV + p * 8;

  for (;;) {
    int t;
    if (wlane == 0) t = atomicAdd(&nextT, 1);
    t = __shfl(t, 0);
    if (t >= 16) break;
    int wid = rowBase + t;
    float4 qv = *(const float4*)(q + (size_t)wid * DIM + p * 4);
    float qx = qv.x * SCALE, qy = qv.y * SCALE, qz = qv.z * SCALE, qw = qv.w * SCALE;
    float l = 0.f, o0 = 0.f, o1 = 0.f, o2 = 0.f, o3 = 0.f;
    int beg = rowptr[wid], end = rowptr[wid + 1];

#define EDGE2(d, wgt)                                                        \
  {                                                                          \
    float k0 = __uint_as_float((d).x << 16);                                 \
    float k1 = __uint_as_float((d).x & 0xffff0000u);                         \
    float k2 = __uint_as_float((d).y << 16);                                 \
    float k3 = __uint_as_float((d).y & 0xffff0000u);                         \
    float part = fmaf(k1, qy, k0 * qx);                                      \
    part = fmaf(k3, qw, fmaf(k2, qz, part));                                 \
    part += __shfl_xor(part, 1);                                             \
    part += __shfl_xor(part, 2);                                             \
    float e = exp2f(part) * (wgt);                                           \
    l += e;                                                                  \
    o0 = fmaf(e, __uint_as_float((d).z << 16), o0);                          \
    o1 = fmaf(e, __uint_as_float((d).z & 0xffff0000u), o1);                  \
    o2 = fmaf(e, __uint_as_float((d).w << 16), o2);                          \
    o3 = fmaf(e, __uint_as_float((d).w & 0xffff0000u), o3);                  \
  }

    int i = beg;
    for (; i + 8 <= end; i += 8) {
      int4 sa = *(const int4*)(esrc + i);  // wave-uniform
      int4 sb = *(const int4*)(esrc + i + 4);
      int s0 = half ? sa.y : sa.x;
      int s1 = half ? sa.w : sa.z;
      int s2 = half ? sb.y : sb.x;
      int s3 = half ? sb.w : sb.z;
      uint4 d0 = *(const uint4*)(base + (size_t)s0 * 256);
      uint4 d1 = *(const uint4*)(base + (size_t)s1 * 256);
      uint4 d2 = *(const uint4*)(base + (size_t)s2 * 256);
      uint4 d3 = *(const uint4*)(base + (size_t)s3 * 256);
      EDGE2(d0, 1.f) EDGE2(d1, 1.f) EDGE2(d2, 1.f) EDGE2(d3, 1.f)
    }
    for (; i + 2 <= end; i += 2) {
      int s = esrc[i + half];
      uint4 d = *(const uint4*)(base + (size_t)s * 256);
      EDGE2(d, 1.f)
    }
    if (i < end) {  // odd tail: both halves load the same edge; half 1 masked out
      int s = esrc[i];
      uint4 d = *(const uint4*)(base + (size_t)s * 256);
      float hm = half ? 0.f : 1.f;
      EDGE2(d, hm)
    }
#undef EDGE2

    // combine the two halves
    l += __shfl_xor(l, 32);
    o0 += __shfl_xor(o0, 32);
    o1 += __shfl_xor(o1, 32);
    o2 += __shfl_xor(o2, 32);
    o3 += __shfl_xor(o3, 32);

    float inv = __builtin_amdgcn_rcpf(l + 1e-16f);
    if (half == 0) {
      ushort4 r4;
      r4.x = f2bf(o0 * inv);
      r4.y = f2bf(o1 * inv);
      r4.z = f2bf(o2 * inv);
      r4.w = f2bf(o3 * inv);
      *(ushort4*)(&tile[t][p * 4]) = r4;
    }
  }
  __syncthreads();

  // ---- o_proj epilogue: 16 rows x 128 cols; wave w does col-tiles 2w, 2w+1 ----
  int w = tid >> 6;
  int m = wlane & 15, quad = wlane >> 4;
  short8 af0 = *(const short8*)(&tile[m][quad * 8]);
  short8 af1 = *(const short8*)(&tile[m][quad * 8 + 32]);
  short8 af2 = *(const short8*)(&tile[m][quad * 8 + 64]);
  short8 af3 = *(const short8*)(&tile[m][quad * 8 + 96]);
#pragma unroll
  for (int c2 = 0; c2 < 2; c2++) {
    int ct = w * 2 + c2;
    int c0 = ct * 16;
    const unsigned short* wp = Wo + (size_t)(c0 + m) * DIM + quad * 8;
    f32x4 acc = {0.f, 0.f, 0.f, 0.f};
    acc = __builtin_amdgcn_mfma_f32_16x16x32_bf16(af0, *(const short8*)(wp), acc, 0, 0, 0);
    acc = __builtin_amdgcn_mfma_f32_16x16x32_bf16(af1, *(const short8*)(wp + 32), acc, 0, 0, 0);
    acc = __builtin_amdgcn_mfma_f32_16x16x32_bf16(af2, *(const short8*)(wp + 64), acc, 0, 0, 0);
    acc = __builtin_amdgcn_mfma_f32_16x16x32_bf16(af3, *(const short8*)(wp + 96), acc, 0, 0, 0);
    float bb = bo[c0 + m];
#pragma unroll
    for (int r = 0; r < 4; r++) {
      int rr = rowBase + quad * 4 + r;
      out[(size_t)rr * DIM + c0 + m] = acc[r] + bb;
    }
  }
}

// ---------------- launch ----------------

extern "C" void kernel_launch(void* const* d_in, const int* in_sizes, int n_in,
                              void* d_out, int out_size, void* d_ws, size_t ws_size,
                              hipStream_t stream) {
  const float* q  = (const float*)d_in[0];
  const float* kv = (const float*)d_in[1];
  const int* ei   = (const int*)d_in[2];
  const float* Wk = (const float*)d_in[3];
  const float* bk = (const float*)d_in[4];
  const float* Wv = (const float*)d_in[5];
  const float* bv = (const float*)d_in[6];
  const float* Wo = (const float*)d_in[7];
  const float* bo = (const float*)d_in[8];
  float* out = (float*)d_out;
  const int* srcp = ei;            // edge_index[0]
  const int* dstp = ei + N_EDGES;  // edge_index[1]

  char* ws = (char*)d_ws;
  size_t o = 0;
  auto alloc = [&](size_t bytes) {
    void* p = ws + o;
    o += (bytes + 511) & ~(size_t)511;
    return p;
  };
  unsigned short* Wkb = (unsigned short*)alloc((size_t)DIM * DIM * 2);      // contiguous:
  unsigned short* Wvb = (unsigned short*)alloc((size_t)DIM * DIM * 2);      //   32768 B each
  unsigned short* Wob = (unsigned short*)alloc((size_t)DIM * DIM * 2);
  unsigned short* KV  = (unsigned short*)alloc((size_t)N_NODES * 256 * 2);  // 51.2 MB
  int* esrc      = (int*)alloc((size_t)N_EDGES * 4);
  unsigned* binned = (unsigned*)alloc((size_t)N_EDGES * 4);                 // 6.4 MB
  int* rowptr    = (int*)alloc((size_t)(N_NODES + 1) * 4);
  int* bcnt      = (int*)alloc((size_t)NB * 4);
  int* binBase   = (int*)alloc((size_t)(NB + 1) * 4);
  int* binNext   = (int*)alloc((size_t)NB * 4);
  (void)ws_size;  // ~66 MB

  hipMemsetAsync(bcnt, 0, (size_t)NB * 4, stream);
  cvt3_kernel<<<48, 256, 0, stream>>>(Wk, Wv, Wo, Wkb);  // Wkb|Wvb|Wob contiguous
  // CSR build: coarse-bucket histogram -> scan -> bin -> per-bucket fine scatter
  int nbblk = (N_EDGES + S1_EDGES - 1) / S1_EDGES;  // 391
  bhist_kernel<<<nbblk, 512, 0, stream>>>(dstp, bcnt);
  bscan_kernel<<<1, 256, 0, stream>>>(bcnt, binBase, binNext);
  bin_kernel<<<nbblk, 512, 0, stream>>>(srcp, dstp, binNext, binned);
  fine_kernel<<<NB, 512, 0, stream>>>(binned, binBase, rowptr, esrc);
  // projections + attention (fused attn + o_proj; two half-grid launches so the
  // slowest dispatch drops to ~60us and top-5 profiling exposes the #2 kernel)
  kv_proj_mfma<<<(N_NODES + 63) / 64, 256, 0, stream>>>(kv, Wkb, bk, Wvb, bv, KV, N_NODES);
  attn_oproj_kernel<<<3125, 256, 0, stream>>>(q, KV, rowptr, esrc, Wob, bo, out, 0);
  attn_oproj_kernel<<<3125, 256, 0, stream>>>(q, KV, rowptr, esrc, Wob, bo, out, 50000);
}